// Round 3
// baseline (721.823 us; speedup 1.0000x reference)
//
#include <hip/hip_runtime.h>
#include <hip/hip_bf16.h>
#include <math.h>

#define N_PART 512
#define T_STEPS 128
#define G_NODES 17
#define ROWS (T_STEPS * G_NODES)   // 2176
#define V_L 3.4f
#define V_0 4.2f
#define GAMMA 0.9f
#define ALPHA 0.15f
#define BETA 15.0f
#define E_CRIT_INV 2e-5f
#define F_STD 0.05f
#define G_STD 0.02f

__device__ __forceinline__ float sigmoid_jax(float x) {
    if (x >= 0.f) return 1.f / (1.f + expf(-x));
    float e = expf(x);
    return e / (1.f + e);
}

__device__ __forceinline__ float vocf(float s) {
    float e1 = expf(GAMMA * (s - 1.f));
    float e2 = expf(-BETA * sqrtf(s));
    return V_L + (V_0 - V_L) * e1 + ALPHA * V_L * (s - 1.f)
         + (1.f - ALPHA) * V_L * (expf(-BETA) - e2);
}

// ---------------------------------------------------------------------------
// Phase A: tabulate Z_t(s_g) partial dots. 2176 rows (t,g), 17 s-nodes, h=1/16.
// Grid 272 blocks: rowblk = bx>>1 (16 rows), colhalf = bx&1 (256 cols).
// zpart[colhalf*ROWS + r] = sum over its 256 cols of w3[c]*sigmoid(h1@w2 + b2).
// ---------------------------------------------------------------------------
#define BKT 16
__global__ __launch_bounds__(256) void k_tab(
    const float* __restrict__ current, const float* __restrict__ w1,
    const float* __restrict__ b1, const float* __restrict__ w2,
    const float* __restrict__ b2, const float* __restrict__ w3,
    float* __restrict__ zpart)
{
    const int tid = threadIdx.x;
    const int rowblk = blockIdx.x >> 1;
    const int colhalf = blockIdx.x & 1;
    const int r0 = rowblk * 16;
    const int cbase = colhalf * 256;

    __shared__ float As[16][BKT + 1];
    __shared__ float Bs[BKT][256];
    __shared__ float srow[16], irow[16];

    if (tid < 16) {
        int r = r0 + tid;
        int t = r / G_NODES;
        int g = r - t * G_NODES;
        srow[tid] = (float)g * (1.0f / 16.0f);
        irow[tid] = current[t];
    }
    __syncthreads();

    const int rg = tid >> 5;   // 0..7 -> rows rg*2, rg*2+1
    const int ct = tid & 31;   // cols cbase + ct*4 + {0..3} + {0,128}
    float acc[2][8];
    #pragma unroll
    for (int a = 0; a < 2; ++a)
        #pragma unroll
        for (int b = 0; b < 8; ++b) acc[a][b] = 0.f;

    const int arow = tid >> 4, ak = tid & 15;

    for (int kk = 0; kk < 1024; kk += BKT) {
        {
            int kc = kk + ak;
            float pre = srow[arow] * w1[kc] + irow[arow] * w1[1024 + kc] + b1[kc];
            As[arow][ak] = sigmoid_jax(pre);
        }
        #pragma unroll
        for (int jj = 0; jj < 4; ++jj) {
            int vi = tid + jj * 256;
            int k = vi >> 6, c4 = vi & 63;
            *(float4*)&Bs[k][c4 * 4] = *(const float4*)&w2[(kk + k) * 512 + cbase + c4 * 4];
        }
        __syncthreads();
        #pragma unroll
        for (int k = 0; k < BKT; ++k) {
            float a0 = As[rg * 2][k];
            float a1 = As[rg * 2 + 1][k];
            float bq[8];
            *(float4*)&bq[0] = *(const float4*)&Bs[k][ct * 4];
            *(float4*)&bq[4] = *(const float4*)&Bs[k][ct * 4 + 128];
            #pragma unroll
            for (int q = 0; q < 8; ++q) {
                acc[0][q] += a0 * bq[q];
                acc[1][q] += a1 * bq[q];
            }
        }
        __syncthreads();
    }

    float b2r[8], w3r[8];
    *(float4*)&b2r[0] = *(const float4*)&b2[cbase + ct * 4];
    *(float4*)&b2r[4] = *(const float4*)&b2[cbase + ct * 4 + 128];
    *(float4*)&w3r[0] = *(const float4*)&w3[cbase + ct * 4];
    *(float4*)&w3r[4] = *(const float4*)&w3[cbase + ct * 4 + 128];
    float zp0 = 0.f, zp1 = 0.f;
    #pragma unroll
    for (int q = 0; q < 8; ++q) {
        zp0 += w3r[q] * sigmoid_jax(acc[0][q] + b2r[q]);
        zp1 += w3r[q] * sigmoid_jax(acc[1][q] + b2r[q]);
    }
    #pragma unroll
    for (int mm = 1; mm < 32; mm <<= 1) {
        zp0 += __shfl_xor(zp0, mm);
        zp1 += __shfl_xor(zp1, mm);
    }
    if (ct == 0) {
        zpart[colhalf * ROWS + r0 + rg * 2] = zp0;
        zpart[colhalf * ROWS + r0 + rg * 2 + 1] = zp1;
    }
}

// cubic Lagrange on 17-node grid, h = 1/16
__device__ __forceinline__ float interp_z(const float* __restrict__ row, float s) {
    float x = s * 16.0f;
    int j = (int)floorf(x);
    j = j < 0 ? 0 : (j > 15 ? 15 : j);
    int st = j - 1;
    st = st < 0 ? 0 : (st > 13 ? 13 : st);
    float uu = x - (float)st;
    float um0 = uu, um1 = uu - 1.f, um2 = uu - 2.f, um3 = uu - 3.f;
    float w0 = um1 * um2 * um3 * (-1.f / 6.f);
    float w1 = um0 * um2 * um3 * (0.5f);
    float w2 = um0 * um1 * um3 * (-0.5f);
    float w3 = um0 * um1 * um2 * (1.f / 6.f);
    return w0 * row[st] + w1 * row[st + 1] + w2 * row[st + 2] + w3 * row[st + 3];
}

// exact count of slots i in [0,512) with fl(i+u) <= C  (= searchsorted inversion)
__device__ __forceinline__ int count_le(float C, float u) {
    int h = (int)floorf(C - u);
    h = h < -1 ? -1 : (h > 511 ? 511 : h);
    while (h < 511 && ((float)(h + 1) + u) <= C) ++h;
    while (h >= 0 && ((float)h + u) > C) --h;
    return h + 1;
}

// ---------------------------------------------------------------------------
// Phase B: whole sequential filter, 1 block, 256 threads, 2 particles/lane.
// ---------------------------------------------------------------------------
__global__ __launch_bounds__(256, 1) void k_seq(
    const float* __restrict__ zpart, const float* __restrict__ soc_init,
    const float* __restrict__ current, const float* __restrict__ vmeas,
    const float* __restrict__ u, const float* __restrict__ noise,
    const float* __restrict__ b3, float* __restrict__ out)
{
    const int tid = threadIdx.x;
    const int lane = tid & 63;
    const int wid = tid >> 6;
    const int p0 = tid * 2;

    __shared__ float zt[ROWS];
    __shared__ float socs_r[512];
    __shared__ float cur_s[128], vm_s[128], u_s[128];
    __shared__ float redM[4], redS[4], redT[4];
    __shared__ int redH[4];

    float bb3 = b3[0];
    for (int j = tid; j < ROWS; j += 256) zt[j] = zpart[j] + zpart[ROWS + j] + bb3;
    if (tid < 128) { cur_s[tid] = current[tid]; vm_s[tid] = vmeas[tid]; u_s[tid] = u[tid]; }
    __syncthreads();

    float soc0 = soc_init[p0];
    float soc1 = soc_init[p0 + 1];
    float I0 = cur_s[0];
    float V0 = vocf(soc0) - I0 * interp_z(&zt[0], soc0);
    float V1 = vocf(soc1) - I0 * interp_z(&zt[0], soc1);
    float Iprev = I0;
    float loss_acc = 0.f;
    const float LOG_NU = logf(19.947114020071635f);
    const float LOG_N = logf(512.f);

    for (int t = 0; t < T_STEPS; ++t) {
        const float* ztr = &zt[t * G_NODES];
        float2 nz = *(const float2*)&noise[t * 512 + p0];

        soc0 = soc0 - Iprev * V0 * E_CRIT_INV + F_STD * nz.x;
        soc1 = soc1 - Iprev * V1 * E_CRIT_INV + F_STD * nz.y;
        soc0 = soc0 > 1.f ? 1.f : (soc0 < 0.f ? 1e-10f : soc0);
        soc1 = soc1 > 1.f ? 1.f : (soc1 < 0.f ? 1e-10f : soc1);

        float I = cur_s[t];
        V0 = vocf(soc0) - I * interp_z(ztr, soc0);
        V1 = vocf(soc1) - I * interp_z(ztr, soc1);
        float vm = vm_s[t];
        float d0 = (V0 - vm) * (1.f / G_STD);
        float d1 = (V1 - vm) * (1.f / G_STD);
        float lw0 = LOG_NU - 0.5f * d0 * d0;
        float lw1 = LOG_NU - 0.5f * d1 * d1;

        // global max
        float m = fmaxf(lw0, lw1);
        #pragma unroll
        for (int mm = 1; mm < 64; mm <<= 1) m = fmaxf(m, __shfl_xor(m, mm));
        if (lane == 0) redM[wid] = m;
        __syncthreads();
        float M = fmaxf(fmaxf(redM[0], redM[1]), fmaxf(redM[2], redM[3]));

        // global sum of exp
        float e0 = expf(lw0 - M);
        float e1 = expf(lw1 - M);
        float s = e0 + e1;
        #pragma unroll
        for (int mm = 1; mm < 64; mm <<= 1) s += __shfl_xor(s, mm);
        if (lane == 0) redS[wid] = s;
        __syncthreads();
        float S = ((redS[0] + redS[1]) + redS[2]) + redS[3];
        loss_acc += M + logf(S) - LOG_N;

        // normalized weights + global inclusive scan
        float wn0 = e0 / S;
        float wn1 = e1 / S;
        float c0 = wn0;
        float c1 = wn0 + wn1;
        float tot = c1;
        float incl = tot;
        #pragma unroll
        for (int dd = 1; dd < 64; dd <<= 1) {
            float tmp = __shfl_up(incl, dd);
            incl += (lane >= dd) ? tmp : 0.f;
        }
        if (lane == 63) redT[wid] = incl;
        __syncthreads();
        float off = 0.f;
        #pragma unroll
        for (int w = 0; w < 4; ++w) off += (w < wid) ? redT[w] : 0.f;
        float base = off + (incl - tot);
        float C0 = 512.f * (base + c0);
        float C1 = 512.f * (base + c1);

        // slot counts (exact searchsorted inversion)
        float ut = u_s[t];
        int hi0 = count_le(C0, ut);
        int hi1 = (tid == 255) ? 512 : count_le(C1, ut);
        if (lane == 63) redH[wid] = hi1;
        __syncthreads();
        int hiprev = __shfl_up(hi1, 1);
        int lo0 = (lane == 0) ? ((wid == 0) ? 0 : redH[wid - 1]) : hiprev;
        int lo1 = hi0;

        // scatter resampled soc
        for (int s2 = lo0; s2 < hi0; ++s2) socs_r[s2] = soc0;
        for (int s2 = lo1; s2 < hi1; ++s2) socs_r[s2] = soc1;
        __syncthreads();

        float2 sr = *(const float2*)&socs_r[p0];
        out[1 + p0 * T_STEPS + t] = V0;
        out[1 + (p0 + 1) * T_STEPS + t] = V1;
        out[1 + N_PART * T_STEPS + p0 * T_STEPS + t] = sr.x;
        out[1 + N_PART * T_STEPS + (p0 + 1) * T_STEPS + t] = sr.y;
        soc0 = sr.x;
        soc1 = sr.y;
        Iprev = I;
    }
    if (tid == 0) out[0] = loss_acc;
}

extern "C" void kernel_launch(void* const* d_in, const int* in_sizes, int n_in,
                              void* d_out, int out_size, void* d_ws, size_t ws_size,
                              hipStream_t stream)
{
    const float* soc_init = (const float*)d_in[0];
    const float* current  = (const float*)d_in[1];
    const float* vmeas    = (const float*)d_in[2];
    const float* noise    = (const float*)d_in[3];
    const float* u        = (const float*)d_in[4];
    const float* w1 = (const float*)d_in[5];
    const float* b1 = (const float*)d_in[6];
    const float* w2 = (const float*)d_in[7];
    const float* b2 = (const float*)d_in[8];
    const float* w3 = (const float*)d_in[9];
    const float* b3 = (const float*)d_in[10];
    float* out = (float*)d_out;
    float* zpart = (float*)d_ws;   // 2*ROWS floats

    k_tab<<<272, 256, 0, stream>>>(current, w1, b1, w2, b2, w3, zpart);
    k_seq<<<1, 256, 0, stream>>>(zpart, soc_init, current, vmeas, u, noise, b3, out);
}

// Round 4
// 550.930 us; speedup vs baseline: 1.3102x; 1.3102x over previous
//
#include <hip/hip_runtime.h>
#include <hip/hip_bf16.h>
#include <math.h>

#define N_PART 512
#define T_STEPS 128
#define G_NODES 33
#define ROWS (T_STEPS * G_NODES)   // 4224
#define V_L 3.4f
#define V_0 4.2f
#define GAMMA 0.9f
#define ALPHA 0.15f
#define BETA 15.0f
#define E_CRIT_INV 2e-5f
#define F_STD 0.05f
#define G_STD 0.02f

__device__ __forceinline__ float sigmoid_jax(float x) {
    if (x >= 0.f) return 1.f / (1.f + expf(-x));
    float e = expf(x);
    return e / (1.f + e);
}

__device__ __forceinline__ float vocf(float s) {
    float e1 = expf(GAMMA * (s - 1.f));
    float e2 = expf(-BETA * sqrtf(s));
    return V_L + (V_0 - V_L) * e1 + ALPHA * V_L * (s - 1.f)
         + (1.f - ALPHA) * V_L * (expf(-BETA) - e2);
}

// ---------------------------------------------------------------------------
// Phase A: tabulate Z_t(s_g) partial dots. 4224 rows (t,g), 33 s-nodes, h=1/32.
// Grid 528 blocks: rowblk = bx>>1 (16 rows), colhalf = bx&1 (256 cols).
// ---------------------------------------------------------------------------
#define BKT 32
__global__ __launch_bounds__(256) void k_tab(
    const float* __restrict__ current, const float* __restrict__ w1,
    const float* __restrict__ b1, const float* __restrict__ w2,
    const float* __restrict__ b2, const float* __restrict__ w3,
    float* __restrict__ zpart)
{
    const int tid = threadIdx.x;
    const int rowblk = blockIdx.x >> 1;
    const int colhalf = blockIdx.x & 1;
    const int r0 = rowblk * 16;
    const int cbase = colhalf * 256;

    __shared__ float As[16][BKT + 1];
    __shared__ float Bs[BKT][256];
    __shared__ float srow[16], irow[16];

    if (tid < 16) {
        int r = r0 + tid;
        int t = r / G_NODES;
        int g = r - t * G_NODES;
        srow[tid] = (float)g * (1.0f / 32.0f);
        irow[tid] = current[t];
    }
    __syncthreads();

    const int rg = tid >> 5;   // 0..7 -> rows rg*2, rg*2+1
    const int ct = tid & 31;   // cols cbase + ct*4 + {0..3} + {0,128}
    float acc[2][8];
    #pragma unroll
    for (int a = 0; a < 2; ++a)
        #pragma unroll
        for (int b = 0; b < 8; ++b) acc[a][b] = 0.f;

    for (int kk = 0; kk < 1024; kk += BKT) {
        #pragma unroll
        for (int half = 0; half < 2; ++half) {
            int idx = tid + half * 256;
            int row = idx >> 5, k = idx & 31;
            int kc = kk + k;
            float pre = srow[row] * w1[kc] + irow[row] * w1[1024 + kc] + b1[kc];
            As[row][k] = sigmoid_jax(pre);
        }
        #pragma unroll
        for (int jj = 0; jj < 8; ++jj) {
            int vi = tid + jj * 256;
            int k = vi >> 6, c4 = vi & 63;
            *(float4*)&Bs[k][c4 * 4] = *(const float4*)&w2[(kk + k) * 512 + cbase + c4 * 4];
        }
        __syncthreads();
        #pragma unroll
        for (int k = 0; k < BKT; ++k) {
            float a0 = As[rg * 2][k];
            float a1 = As[rg * 2 + 1][k];
            float bq[8];
            *(float4*)&bq[0] = *(const float4*)&Bs[k][ct * 4];
            *(float4*)&bq[4] = *(const float4*)&Bs[k][ct * 4 + 128];
            #pragma unroll
            for (int q = 0; q < 8; ++q) {
                acc[0][q] += a0 * bq[q];
                acc[1][q] += a1 * bq[q];
            }
        }
        __syncthreads();
    }

    float b2r[8], w3r[8];
    *(float4*)&b2r[0] = *(const float4*)&b2[cbase + ct * 4];
    *(float4*)&b2r[4] = *(const float4*)&b2[cbase + ct * 4 + 128];
    *(float4*)&w3r[0] = *(const float4*)&w3[cbase + ct * 4];
    *(float4*)&w3r[4] = *(const float4*)&w3[cbase + ct * 4 + 128];
    float zp0 = 0.f, zp1 = 0.f;
    #pragma unroll
    for (int q = 0; q < 8; ++q) {
        zp0 += w3r[q] * sigmoid_jax(acc[0][q] + b2r[q]);
        zp1 += w3r[q] * sigmoid_jax(acc[1][q] + b2r[q]);
    }
    #pragma unroll
    for (int mm = 1; mm < 32; mm <<= 1) {
        zp0 += __shfl_xor(zp0, mm);
        zp1 += __shfl_xor(zp1, mm);
    }
    if (ct == 0) {
        zpart[colhalf * ROWS + r0 + rg * 2] = zp0;
        zpart[colhalf * ROWS + r0 + rg * 2 + 1] = zp1;
    }
}

// cubic Lagrange on 33-node grid, h = 1/32
__device__ __forceinline__ float interp_z(const float* __restrict__ row, float s) {
    float x = s * 32.0f;
    int j = (int)floorf(x);
    j = j < 0 ? 0 : (j > 31 ? 31 : j);
    int st = j - 1;
    st = st < 0 ? 0 : (st > 29 ? 29 : st);
    float uu = x - (float)st;
    float um0 = uu, um1 = uu - 1.f, um2 = uu - 2.f, um3 = uu - 3.f;
    float w0 = um1 * um2 * um3 * (-1.f / 6.f);
    float w1 = um0 * um2 * um3 * (0.5f);
    float w2 = um0 * um1 * um3 * (-0.5f);
    float w3 = um0 * um1 * um2 * (1.f / 6.f);
    return w0 * row[st] + w1 * row[st + 1] + w2 * row[st + 2] + w3 * row[st + 3];
}

// exact count of slots i in [0,512) with fl(i+u) <= C
__device__ __forceinline__ int count_le(float C, float u) {
    int h = (int)floorf(C - u);
    h = h < -1 ? -1 : (h > 511 ? 511 : h);
    while (h < 511 && ((float)(h + 1) + u) <= C) ++h;
    while (h >= 0 && ((float)h + u) > C) --h;
    return h + 1;
}

// ---------------------------------------------------------------------------
// Phase B: whole filter, 1 block, 512 threads (1 particle/lane), 4 barriers/step.
// ---------------------------------------------------------------------------
__global__ __launch_bounds__(512, 1) void k_seq(
    const float* __restrict__ zpart, const float* __restrict__ soc_init,
    const float* __restrict__ current, const float* __restrict__ vmeas,
    const float* __restrict__ u, const float* __restrict__ noise,
    const float* __restrict__ b3, float* __restrict__ out)
{
    const int tid = threadIdx.x;
    const int lane = tid & 63;
    const int wid = tid >> 6;

    __shared__ float zt[ROWS];
    __shared__ float socs[2][512];
    __shared__ int marker[512];
    __shared__ float cur_s[128], vm_s[128], u_s[128];
    __shared__ float redM[8], redT[8];
    __shared__ int redX[8];

    float bb3 = b3[0];
    for (int j = tid; j < ROWS; j += 512) zt[j] = zpart[j] + zpart[ROWS + j] + bb3;
    if (tid < 128) { cur_s[tid] = current[tid]; vm_s[tid] = vmeas[tid]; u_s[tid] = u[tid]; }
    marker[tid] = 0;
    __syncthreads();

    float soc = soc_init[tid];
    float Iprev = cur_s[0];
    float V = vocf(soc) - Iprev * interp_z(&zt[0], soc);
    float loss_acc = 0.f;
    const float LOG_NU = logf(19.947114020071635f);
    const float LOG_N = logf(512.f);

    float nz_cur = noise[tid];

    for (int t = 0; t < T_STEPS; ++t) {
        // prefetch next step's noise (hides HBM/L2 latency under this step)
        int tn = (t + 1 < T_STEPS) ? t + 1 : t;
        float nz_next = noise[tn * 512 + tid];

        // ---- A: propagate, V, logW, wave-max ----
        soc = soc - Iprev * V * E_CRIT_INV + F_STD * nz_cur;
        soc = soc > 1.f ? 1.f : (soc < 0.f ? 1e-10f : soc);
        socs[t & 1][tid] = soc;

        float I = cur_s[t];
        V = vocf(soc) - I * interp_z(&zt[t * G_NODES], soc);
        float d = (V - vm_s[t]) * (1.f / G_STD);
        float lw = LOG_NU - 0.5f * d * d;

        float m = lw;
        #pragma unroll
        for (int mm = 1; mm < 64; mm <<= 1) m = fmaxf(m, __shfl_xor(m, mm));
        if (lane == 0) redM[wid] = m;
        __syncthreads();                                   // barrier 1

        // ---- B: global max, exp, wave scan (subsumes sum) ----
        float M = redM[0];
        #pragma unroll
        for (int w = 1; w < 8; ++w) M = fmaxf(M, redM[w]);
        float e = expf(lw - M);
        float incl = e;
        #pragma unroll
        for (int dd = 1; dd < 64; dd <<= 1) {
            float tmp = __shfl_up(incl, dd);
            incl += (lane >= dd) ? tmp : 0.f;
        }
        if (lane == 63) redT[wid] = incl;
        __syncthreads();                                   // barrier 2

        // ---- C: cross-wave offsets, slot range, marker write ----
        float off = 0.f, S = 0.f;
        #pragma unroll
        for (int w = 0; w < 8; ++w) {
            float v = redT[w];
            if (w < wid) off += v;    // left-to-right partial: bit-matches lane0 Cp below
            S += v;
        }
        loss_acc += M + logf(S) - LOG_N;

        float C = 512.f * ((off + incl) / S);
        float Cp = __shfl_up(C, 1);
        if (lane == 0) Cp = 512.f * (off / S);
        float ut = u_s[t];
        int hi = (tid == 511) ? 512 : count_le(C, ut);
        int lo = (tid == 0) ? 0 : count_le(Cp, ut);
        if (hi > lo) marker[lo] = ((t + 1) << 10) | tid;
        __syncthreads();                                   // barrier 3

        // ---- D: max-scan over slot markers ----
        int v = marker[tid];
        #pragma unroll
        for (int dd = 1; dd < 64; dd <<= 1) {
            int tmp = __shfl_up(v, dd);
            v = (lane >= dd && tmp > v) ? tmp : v;
        }
        if (lane == 63) redX[wid] = v;
        __syncthreads();                                   // barrier 4

        // ---- E: owner, gather, outputs ----
        int pm = 0;
        #pragma unroll
        for (int w = 0; w < 8; ++w) {
            int x = redX[w];
            if (w < wid && x > pm) pm = x;
        }
        int owner = (v > pm ? v : pm) & 1023;
        float socr = socs[t & 1][owner];

        out[1 + tid * T_STEPS + t] = V;
        out[1 + N_PART * T_STEPS + tid * T_STEPS + t] = socr;
        soc = socr;
        Iprev = I;
        nz_cur = nz_next;
    }
    if (tid == 0) out[0] = loss_acc;
}

extern "C" void kernel_launch(void* const* d_in, const int* in_sizes, int n_in,
                              void* d_out, int out_size, void* d_ws, size_t ws_size,
                              hipStream_t stream)
{
    const float* soc_init = (const float*)d_in[0];
    const float* current  = (const float*)d_in[1];
    const float* vmeas    = (const float*)d_in[2];
    const float* noise    = (const float*)d_in[3];
    const float* u        = (const float*)d_in[4];
    const float* w1 = (const float*)d_in[5];
    const float* b1 = (const float*)d_in[6];
    const float* w2 = (const float*)d_in[7];
    const float* b2 = (const float*)d_in[8];
    const float* w3 = (const float*)d_in[9];
    const float* b3 = (const float*)d_in[10];
    float* out = (float*)d_out;
    float* zpart = (float*)d_ws;   // 2*ROWS floats

    k_tab<<<528, 256, 0, stream>>>(current, w1, b1, w2, b2, w3, zpart);
    k_seq<<<1, 512, 0, stream>>>(zpart, soc_init, current, vmeas, u, noise, b3, out);
}

// Round 6
// 370.467 us; speedup vs baseline: 1.9484x; 1.4871x over previous
//
#include <hip/hip_runtime.h>
#include <hip/hip_bf16.h>
#include <math.h>

#define N_PART 512
#define T_STEPS 128
#define G_NODES 33
#define ROWS (T_STEPS * G_NODES)   // 4224
#define V_L 3.4f
#define V_0 4.2f
#define GAMMA 0.9f
#define ALPHA 0.15f
#define BETA 15.0f
#define E_CRIT_INV 2e-5f
#define F_STD 0.05f
#define G_STD 0.02f

__device__ __forceinline__ float sigmoid_jax(float x) {
    float e = expf(-fabsf(x));
    float num = (x >= 0.f) ? 1.f : e;
    return num / (1.f + e);
}

__device__ __forceinline__ float vocf(float s) {
    float sm1 = s - 1.f;
    return V_L + (V_0 - V_L) * expf(GAMMA * sm1)
         + (ALPHA * V_L) * sm1
         + (1.f - ALPHA) * V_L * (expf(-BETA) - expf(-BETA * sqrtf(s)));
}

// ---------------- DPP cross-lane helpers (VALU pipe, no LDS latency) --------
template <int R>
__device__ __forceinline__ int dpp_ror(int v) {
    return __builtin_amdgcn_update_dpp(0, v, 0x120 | R, 0xf, 0xf, false);
}
template <int S>
__device__ __forceinline__ int dpp_shr(int v) {
    return __builtin_amdgcn_update_dpp(0, v, 0x110 | S, 0xf, 0xf, true);
}

// all-lane max of f32 across wave64 -> uniform value in every lane
__device__ __forceinline__ float wave_max_f(float v) {
    v = fmaxf(v, __int_as_float(dpp_ror<1>(__float_as_int(v))));
    v = fmaxf(v, __int_as_float(dpp_ror<2>(__float_as_int(v))));
    v = fmaxf(v, __int_as_float(dpp_ror<4>(__float_as_int(v))));
    v = fmaxf(v, __int_as_float(dpp_ror<8>(__float_as_int(v))));
    int iv = __float_as_int(v);
    v = fmaxf(v, __int_as_float(__builtin_amdgcn_update_dpp(iv, iv, 0x142, 0xf, 0xf, false))); // bcast15
    iv = __float_as_int(v);
    v = fmaxf(v, __int_as_float(__builtin_amdgcn_update_dpp(iv, iv, 0x143, 0xf, 0xf, false))); // bcast31
    return __int_as_float(__builtin_amdgcn_readlane(__float_as_int(v), 63));
}

__device__ __forceinline__ int wave_max_i(int v) {
    v = max(v, dpp_ror<1>(v));
    v = max(v, dpp_ror<2>(v));
    v = max(v, dpp_ror<4>(v));
    v = max(v, dpp_ror<8>(v));
    v = max(v, __builtin_amdgcn_update_dpp(v, v, 0x142, 0xf, 0xf, false));
    v = max(v, __builtin_amdgcn_update_dpp(v, v, 0x143, 0xf, 0xf, false));
    return __builtin_amdgcn_readlane(v, 63);
}

// inclusive add-scan across wave64
__device__ __forceinline__ float wave_scan_add(float v, int lane) {
    v += __int_as_float(dpp_shr<1>(__float_as_int(v)));
    v += __int_as_float(dpp_shr<2>(__float_as_int(v)));
    v += __int_as_float(dpp_shr<4>(__float_as_int(v)));
    v += __int_as_float(dpp_shr<8>(__float_as_int(v)));
    float s15 = __int_as_float(__builtin_amdgcn_readlane(__float_as_int(v), 15));
    float s31 = __int_as_float(__builtin_amdgcn_readlane(__float_as_int(v), 31));
    float s47 = __int_as_float(__builtin_amdgcn_readlane(__float_as_int(v), 47));
    int row = lane >> 4;
    if (row >= 1) v += s15;
    if (row >= 2) v += s31;
    if (row >= 3) v += s47;
    return v;
}

// inclusive max-scan across wave64 (non-negative ints)
__device__ __forceinline__ int wave_scanmax_i(int v, int lane) {
    v = max(v, dpp_shr<1>(v));
    v = max(v, dpp_shr<2>(v));
    v = max(v, dpp_shr<4>(v));
    v = max(v, dpp_shr<8>(v));
    int r15 = __builtin_amdgcn_readlane(v, 15);
    int r31 = __builtin_amdgcn_readlane(v, 31);
    int r47 = __builtin_amdgcn_readlane(v, 47);
    int row = lane >> 4;
    if (row >= 1) v = max(v, r15);
    if (row >= 2) v = max(v, r31);
    if (row >= 3) v = max(v, r47);
    return v;
}

// ---------------------------------------------------------------------------
// Phase A: tabulate Z_t(s_g) partial dots. 4224 rows, 33 s-nodes, h=1/32.
// 264 blocks: rowblk = bx>>1 (32 rows), colhalf = bx&1 (256 cols).
// Thread tile: 4 rows x 8 cols.
// ---------------------------------------------------------------------------
#define BKT 32
__global__ __launch_bounds__(256) void k_tab(
    const float* __restrict__ current, const float* __restrict__ w1,
    const float* __restrict__ b1, const float* __restrict__ w2,
    const float* __restrict__ b2, const float* __restrict__ w3,
    float* __restrict__ zpart)
{
    const int tid = threadIdx.x;
    const int rowblk = blockIdx.x >> 1;
    const int colhalf = blockIdx.x & 1;
    const int r0 = rowblk * 32;
    const int cbase = colhalf * 256;

    __shared__ float As[32][33];
    __shared__ float Bs[BKT][256];
    __shared__ float srow[32], irow[32];

    if (tid < 32) {
        int r = r0 + tid;
        int t = r / G_NODES;
        int g = r - t * G_NODES;
        srow[tid] = (float)g * (1.0f / 32.0f);
        irow[tid] = current[t];
    }
    __syncthreads();

    const int rg = tid >> 5;   // 8 groups -> rows rg*4 + rr
    const int ct = tid & 31;   // cols cbase + ct*4 + {0..3} + {0,128}
    float acc[4][8];
    #pragma unroll
    for (int a = 0; a < 4; ++a)
        #pragma unroll
        for (int b = 0; b < 8; ++b) acc[a][b] = 0.f;

    const int arow = tid >> 5, ak = tid & 31;

    for (int kk = 0; kk < 1024; kk += BKT) {
        #pragma unroll
        for (int q4 = 0; q4 < 4; ++q4) {
            int row = arow + q4 * 8;
            int kc = kk + ak;
            float pre = srow[row] * w1[kc] + irow[row] * w1[1024 + kc] + b1[kc];
            As[row][ak] = sigmoid_jax(pre);
        }
        #pragma unroll
        for (int jj = 0; jj < 8; ++jj) {
            int vi = tid + jj * 256;
            int k = vi >> 6, c4 = vi & 63;
            *(float4*)&Bs[k][c4 * 4] = *(const float4*)&w2[(kk + k) * 512 + cbase + c4 * 4];
        }
        __syncthreads();
        #pragma unroll
        for (int k = 0; k < BKT; ++k) {
            float a0 = As[rg * 4 + 0][k];
            float a1 = As[rg * 4 + 1][k];
            float a2 = As[rg * 4 + 2][k];
            float a3 = As[rg * 4 + 3][k];
            float bq[8];
            *(float4*)&bq[0] = *(const float4*)&Bs[k][ct * 4];
            *(float4*)&bq[4] = *(const float4*)&Bs[k][ct * 4 + 128];
            #pragma unroll
            for (int q = 0; q < 8; ++q) {
                acc[0][q] += a0 * bq[q];
                acc[1][q] += a1 * bq[q];
                acc[2][q] += a2 * bq[q];
                acc[3][q] += a3 * bq[q];
            }
        }
        __syncthreads();
    }

    float b2r[8], w3r[8];
    *(float4*)&b2r[0] = *(const float4*)&b2[cbase + ct * 4];
    *(float4*)&b2r[4] = *(const float4*)&b2[cbase + ct * 4 + 128];
    *(float4*)&w3r[0] = *(const float4*)&w3[cbase + ct * 4];
    *(float4*)&w3r[4] = *(const float4*)&w3[cbase + ct * 4 + 128];
    #pragma unroll
    for (int rr = 0; rr < 4; ++rr) {
        float zp = 0.f;
        #pragma unroll
        for (int q = 0; q < 8; ++q)
            zp += w3r[q] * sigmoid_jax(acc[rr][q] + b2r[q]);
        #pragma unroll
        for (int mm = 1; mm < 32; mm <<= 1) zp += __shfl_xor(zp, mm);
        if (ct == 0) zpart[colhalf * ROWS + r0 + rg * 4 + rr] = zp;
    }
}

// cubic Lagrange on 33-node grid, h = 1/32
__device__ __forceinline__ float interp_z(const float* __restrict__ row, float s) {
    float x = s * 32.0f;
    int j = (int)floorf(x);
    j = j < 0 ? 0 : (j > 31 ? 31 : j);
    int st = j - 1;
    st = st < 0 ? 0 : (st > 29 ? 29 : st);
    float uu = x - (float)st;
    float um0 = uu, um1 = uu - 1.f, um2 = uu - 2.f, um3 = uu - 3.f;
    float w0 = um1 * um2 * um3 * (-1.f / 6.f);
    float w1 = um0 * um2 * um3 * (0.5f);
    float w2 = um0 * um1 * um3 * (-0.5f);
    float w3 = um0 * um1 * um2 * (1.f / 6.f);
    return w0 * row[st] + w1 * row[st + 1] + w2 * row[st + 2] + w3 * row[st + 3];
}

// exact count of slots i in [0,512) with fl(i+u) <= C, branchless +-2 fixup
__device__ __forceinline__ int count_le(float C, float u) {
    int h = (int)floorf(C - u);
    h = h < -1 ? -1 : (h > 511 ? 511 : h);
    h += (int)((h < 511) && (((float)(h + 1) + u) <= C));
    h += (int)((h < 511) && (((float)(h + 1) + u) <= C));
    h -= (int)((h >= 0) && (((float)h + u) > C));
    h -= (int)((h >= 0) && (((float)h + u) > C));
    return h + 1;
}

// ---------------------------------------------------------------------------
// Phase B: whole filter, 1 block, 512 threads, 2 barriers/step, DPP scans,
// coalesced time-major stores to workspace.
// ---------------------------------------------------------------------------
__global__ __launch_bounds__(512, 1) void k_seq(
    const float* __restrict__ zpart, const float* __restrict__ soc_init,
    const float* __restrict__ current, const float* __restrict__ vmeas,
    const float* __restrict__ u, const float* __restrict__ noise,
    const float* __restrict__ b3, float* __restrict__ vbuf,
    float* __restrict__ sbuf, float* __restrict__ out)
{
    const int tid = threadIdx.x;
    const int lane = tid & 63;
    const int wid = tid >> 6;

    __shared__ float zt[ROWS];
    __shared__ float socs[2][512];
    __shared__ int marker[512];
    __shared__ float cur_s[128], vm_s[128], u_s[128];
    __shared__ float redM[8], redT[8];

    float bb3 = b3[0];
    for (int j = tid; j < ROWS; j += 512) zt[j] = zpart[j] + zpart[ROWS + j] + bb3;
    if (tid < 128) { cur_s[tid] = current[tid]; vm_s[tid] = vmeas[tid]; u_s[tid] = u[tid]; }
    marker[tid] = 0;
    __syncthreads();

    float soc = soc_init[tid];
    float Iprev = cur_s[0];
    float V = vocf(soc) - Iprev * interp_z(&zt[0], soc);
    float loss_acc = 0.f;
    const float LOG_NU = logf(19.947114020071635f);
    const float LOG_N = logf(512.f);

    float nz_cur = noise[tid];

    for (int t = 0; t < T_STEPS; ++t) {
        int tn = (t + 1 < T_STEPS) ? t + 1 : t;
        float nz_next = noise[tn * 512 + tid];

        // ---- A: propagate, V, logW, wave max + scan (all DPP) ----
        soc = soc - Iprev * V * E_CRIT_INV + F_STD * nz_cur;
        soc = soc > 1.f ? 1.f : (soc < 0.f ? 1e-10f : soc);
        socs[t & 1][tid] = soc;

        float I = cur_s[t];
        V = vocf(soc) - I * interp_z(&zt[t * G_NODES], soc);
        float d = (V - vm_s[t]) * (1.f / G_STD);
        float lw = LOG_NU - 0.5f * d * d;

        float m = wave_max_f(lw);
        float e = expf(lw - m);
        float incl = wave_scan_add(e, lane);
        if (lane == 63) { redM[wid] = m; redT[wid] = incl; }
        __syncthreads();                                   // barrier 1

        // ---- B: cross-wave combine (scaled sums), slot boundary, marker ----
        float M = redM[0];
        #pragma unroll
        for (int w = 1; w < 8; ++w) M = fmaxf(M, redM[w]);
        float S = 0.f, off = 0.f, fw_own = 0.f;
        #pragma unroll
        for (int w = 0; w < 8; ++w) {
            float fw = expf(redM[w] - M);
            float term = redT[w] * fw;
            if (w < wid) off += term;
            if (w == wid) fw_own = fw;
            S += term;
        }
        loss_acc += M + logf(S) - LOG_N;

        float C = 512.f * ((off + incl * fw_own) / S);
        int hi = count_le(C, u_s[t]);
        if (hi < 512) atomicMax(&marker[hi], (t << 10) | (tid + 1));
        __syncthreads();                                   // barrier 2

        // ---- C: owner via max-scan of markers, gather, coalesced stores ----
        int pm = 0;
        for (int w = 0; w < wid; ++w) pm = max(pm, marker[w * 64 + lane]);
        pm = wave_max_i(pm);
        int v = wave_scanmax_i(marker[tid], lane);
        int sv = max(v, pm);
        int owner = ((sv >> 10) == t) ? (sv & 1023) : 0;
        owner = owner > 511 ? 511 : owner;
        float socr = socs[t & 1][owner];

        vbuf[t * 512 + tid] = V;
        sbuf[t * 512 + tid] = socr;
        soc = socr;
        Iprev = I;
        nz_cur = nz_next;
    }
    if (tid == 0) out[0] = loss_acc;
}

// ---------------------------------------------------------------------------
// Phase C: transpose time-major [128][512] -> particle-major [512][128]
// ---------------------------------------------------------------------------
__global__ __launch_bounds__(256) void k_fin(
    const float* __restrict__ vbuf, const float* __restrict__ sbuf,
    float* __restrict__ out)
{
    __shared__ float tile[32][33];
    int tz = blockIdx.z;
    int t0 = blockIdx.x * 32;
    int i0 = blockIdx.y * 32;
    const float* src = tz ? sbuf : vbuf;
    float* dst = out + 1 + tz * (N_PART * T_STEPS);
    int tx = threadIdx.x & 31, ty = threadIdx.x >> 5;
    #pragma unroll
    for (int m2 = 0; m2 < 4; ++m2)
        tile[ty + 8 * m2][tx] = src[(t0 + ty + 8 * m2) * 512 + i0 + tx];
    __syncthreads();
    #pragma unroll
    for (int m2 = 0; m2 < 4; ++m2)
        dst[(i0 + ty + 8 * m2) * 128 + t0 + tx] = tile[tx][ty + 8 * m2];
}

extern "C" void kernel_launch(void* const* d_in, const int* in_sizes, int n_in,
                              void* d_out, int out_size, void* d_ws, size_t ws_size,
                              hipStream_t stream)
{
    const float* soc_init = (const float*)d_in[0];
    const float* current  = (const float*)d_in[1];
    const float* vmeas    = (const float*)d_in[2];
    const float* noise    = (const float*)d_in[3];
    const float* u        = (const float*)d_in[4];
    const float* w1 = (const float*)d_in[5];
    const float* b1 = (const float*)d_in[6];
    const float* w2 = (const float*)d_in[7];
    const float* b2 = (const float*)d_in[8];
    const float* w3 = (const float*)d_in[9];
    const float* b3 = (const float*)d_in[10];
    float* out = (float*)d_out;
    float* ws  = (float*)d_ws;

    float* zpart = ws;                       // 2*ROWS = 8448 floats
    float* vbuf  = ws + 2 * ROWS;            // 65536 floats
    float* sbuf  = vbuf + N_PART * T_STEPS;  // 65536 floats

    k_tab<<<264, 256, 0, stream>>>(current, w1, b1, w2, b2, w3, zpart);
    k_seq<<<1, 512, 0, stream>>>(zpart, soc_init, current, vmeas, u, noise, b3,
                                 vbuf, sbuf, out);
    k_fin<<<dim3(4, 16, 2), 256, 0, stream>>>(vbuf, sbuf, out);
}

// Round 7
// 286.205 us; speedup vs baseline: 2.5220x; 1.2944x over previous
//
#include <hip/hip_runtime.h>
#include <hip/hip_bf16.h>
#include <math.h>

#define N_PART 512
#define T_STEPS 128
#define G_NODES 33
#define TAB2D (G_NODES * G_NODES)   // 1089
#define ROWS (T_STEPS * G_NODES)    // 4224
#define V_L 3.4f
#define V_0 4.2f
#define GAMMA 0.9f
#define ALPHA 0.15f
#define BETA 15.0f
#define E_CRIT_INV 2e-5f
#define F_STD 0.05f
#define G_STD 0.02f

// light barrier: LDS-ordering only, leaves global loads/stores in flight
#define LBAR() asm volatile("s_waitcnt lgkmcnt(0)\n\ts_barrier" ::: "memory")

__device__ __forceinline__ float sigmoid_jax(float x) {
    float e = expf(-fabsf(x));
    float num = (x >= 0.f) ? 1.f : e;
    return num / (1.f + e);
}

__device__ __forceinline__ float vocf(float s) {
    float sm1 = s - 1.f;
    return V_L + (V_0 - V_L) * expf(GAMMA * sm1)
         + (ALPHA * V_L) * sm1
         + (1.f - ALPHA) * V_L * (expf(-BETA) - expf(-BETA * sqrtf(s)));
}

// ---------------- DPP cross-lane helpers --------------------------------
template <int R>
__device__ __forceinline__ int dpp_ror(int v) {
    return __builtin_amdgcn_update_dpp(0, v, 0x120 | R, 0xf, 0xf, false);
}
template <int S>
__device__ __forceinline__ int dpp_shr(int v) {
    return __builtin_amdgcn_update_dpp(0, v, 0x110 | S, 0xf, 0xf, true);
}
__device__ __forceinline__ float fror(float v, float o) { return o; } // unused

// all-lane max across wave64 -> uniform
__device__ __forceinline__ float wave_max_f(float v) {
    v = fmaxf(v, __int_as_float(dpp_ror<1>(__float_as_int(v))));
    v = fmaxf(v, __int_as_float(dpp_ror<2>(__float_as_int(v))));
    v = fmaxf(v, __int_as_float(dpp_ror<4>(__float_as_int(v))));
    v = fmaxf(v, __int_as_float(dpp_ror<8>(__float_as_int(v))));
    int iv = __float_as_int(v);
    v = fmaxf(v, __int_as_float(__builtin_amdgcn_update_dpp(iv, iv, 0x142, 0xf, 0xf, false))); // bcast15
    iv = __float_as_int(v);
    v = fmaxf(v, __int_as_float(__builtin_amdgcn_update_dpp(iv, iv, 0x143, 0xf, 0xf, false))); // bcast31
    return __int_as_float(__builtin_amdgcn_readlane(__float_as_int(v), 63));
}

__device__ __forceinline__ int wave_max_i(int v) {
    v = max(v, dpp_ror<1>(v));
    v = max(v, dpp_ror<2>(v));
    v = max(v, dpp_ror<4>(v));
    v = max(v, dpp_ror<8>(v));
    v = max(v, __builtin_amdgcn_update_dpp(v, v, 0x142, 0xf, 0xf, false));
    v = max(v, __builtin_amdgcn_update_dpp(v, v, 0x143, 0xf, 0xf, false));
    return __builtin_amdgcn_readlane(v, 63);
}

// inclusive add-scan across wave64
__device__ __forceinline__ float wave_scan_add(float v, int lane) {
    v += __int_as_float(dpp_shr<1>(__float_as_int(v)));
    v += __int_as_float(dpp_shr<2>(__float_as_int(v)));
    v += __int_as_float(dpp_shr<4>(__float_as_int(v)));
    v += __int_as_float(dpp_shr<8>(__float_as_int(v)));
    float s15 = __int_as_float(__builtin_amdgcn_readlane(__float_as_int(v), 15));
    float s31 = __int_as_float(__builtin_amdgcn_readlane(__float_as_int(v), 31));
    float s47 = __int_as_float(__builtin_amdgcn_readlane(__float_as_int(v), 47));
    int row = lane >> 4;
    if (row >= 1) v += s15;
    if (row >= 2) v += s31;
    if (row >= 3) v += s47;
    return v;
}

// inclusive max-scan across wave64 (non-negative ints)
__device__ __forceinline__ int wave_scanmax_i(int v, int lane) {
    v = max(v, dpp_shr<1>(v));
    v = max(v, dpp_shr<2>(v));
    v = max(v, dpp_shr<4>(v));
    v = max(v, dpp_shr<8>(v));
    int r15 = __builtin_amdgcn_readlane(v, 15);
    int r31 = __builtin_amdgcn_readlane(v, 31);
    int r47 = __builtin_amdgcn_readlane(v, 47);
    int row = lane >> 4;
    if (row >= 1) v = max(v, r15);
    if (row >= 2) v = max(v, r31);
    if (row >= 3) v = max(v, r47);
    return v;
}

// ---------------------------------------------------------------------------
// Phase A: 2-D table Z(s_i, I_j) on 33x33 nodes, partial dots per 256-col half.
// Grid: 274 blocks = 137 rowblocks (8 rows) x 2 colhalves. Exact f32 MLP.
// ---------------------------------------------------------------------------
#define BKT 32
__global__ __launch_bounds__(256) void k_tab(
    const float* __restrict__ w1, const float* __restrict__ b1,
    const float* __restrict__ w2, const float* __restrict__ b2,
    const float* __restrict__ w3, float* __restrict__ zpart)
{
    const int tid = threadIdx.x;
    const int rowblk = blockIdx.x >> 1;
    const int colhalf = blockIdx.x & 1;
    const int r0 = rowblk * 8;
    const int cbase = colhalf * 256;

    __shared__ float As[8][BKT + 1];
    __shared__ float Bs[BKT][256];
    __shared__ float srow[8], irow[8];

    if (tid < 8) {
        int r = r0 + tid;
        r = r > (TAB2D - 1) ? (TAB2D - 1) : r;
        int si = r / G_NODES;
        int ii = r - si * G_NODES;
        srow[tid] = (float)si * (1.0f / 32.0f);
        irow[tid] = (float)ii * (1.0f / 32.0f);
    }
    __syncthreads();

    const int rg = tid >> 5;   // 0..7: row within block
    const int ct = tid & 31;   // cols cbase + ct*4 + {0..3} + {0,128}
    float acc[8];
    #pragma unroll
    for (int b = 0; b < 8; ++b) acc[b] = 0.f;

    for (int kk = 0; kk < 1024; kk += BKT) {
        {
            int kc = kk + ct;
            float pre = srow[rg] * w1[kc] + irow[rg] * w1[1024 + kc] + b1[kc];
            As[rg][ct] = sigmoid_jax(pre);
        }
        #pragma unroll
        for (int jj = 0; jj < 8; ++jj) {
            int vi = tid + jj * 256;
            int k = vi >> 6, c4 = vi & 63;
            *(float4*)&Bs[k][c4 * 4] = *(const float4*)&w2[(kk + k) * 512 + cbase + c4 * 4];
        }
        __syncthreads();
        #pragma unroll
        for (int k = 0; k < BKT; ++k) {
            float a = As[rg][k];
            float bq[8];
            *(float4*)&bq[0] = *(const float4*)&Bs[k][ct * 4];
            *(float4*)&bq[4] = *(const float4*)&Bs[k][ct * 4 + 128];
            #pragma unroll
            for (int q = 0; q < 8; ++q) acc[q] += a * bq[q];
        }
        __syncthreads();
    }

    float b2r[8], w3r[8];
    *(float4*)&b2r[0] = *(const float4*)&b2[cbase + ct * 4];
    *(float4*)&b2r[4] = *(const float4*)&b2[cbase + ct * 4 + 128];
    *(float4*)&w3r[0] = *(const float4*)&w3[cbase + ct * 4];
    *(float4*)&w3r[4] = *(const float4*)&w3[cbase + ct * 4 + 128];
    float zp = 0.f;
    #pragma unroll
    for (int q = 0; q < 8; ++q)
        zp += w3r[q] * sigmoid_jax(acc[q] + b2r[q]);
    #pragma unroll
    for (int mm = 1; mm < 32; mm <<= 1) zp += __shfl_xor(zp, mm);
    if (ct == 0 && (r0 + rg) < TAB2D)
        zpart[colhalf * TAB2D + r0 + rg] = zp;
}

// cubic Lagrange on 33-node grid, h = 1/32, stride-able
__device__ __forceinline__ float interp_tab(const float* __restrict__ row, int stride, float s) {
    float x = s * 32.0f;
    int j = (int)floorf(x);
    j = j < 0 ? 0 : (j > 31 ? 31 : j);
    int st = j - 1;
    st = st < 0 ? 0 : (st > 29 ? 29 : st);
    float uu = x - (float)st;
    float um0 = uu, um1 = uu - 1.f, um2 = uu - 2.f, um3 = uu - 3.f;
    float w0 = um1 * um2 * um3 * (-1.f / 6.f);
    float w1 = um0 * um2 * um3 * (0.5f);
    float w2 = um0 * um1 * um3 * (-0.5f);
    float w3 = um0 * um1 * um2 * (1.f / 6.f);
    return w0 * row[st * stride] + w1 * row[(st + 1) * stride]
         + w2 * row[(st + 2) * stride] + w3 * row[(st + 3) * stride];
}

// exact count of slots i in [0,512) with fl(i+u) <= C, branchless +-2 fixup
__device__ __forceinline__ int count_le(float C, float u) {
    int h = (int)floorf(C - u);
    h = h < -1 ? -1 : (h > 511 ? 511 : h);
    h += (int)((h < 511) && (((float)(h + 1) + u) <= C));
    h += (int)((h < 511) && (((float)(h + 1) + u) <= C));
    h -= (int)((h >= 0) && (((float)h + u) > C));
    h -= (int)((h >= 0) && (((float)h + u) > C));
    return h + 1;
}

// ---------------------------------------------------------------------------
// Phase B: whole filter, 1 block, 512 threads, 2 LIGHT barriers/step.
// Preamble collapses the 2-D table to per-t 1-D tables (cubic interp in I).
// ---------------------------------------------------------------------------
__global__ __launch_bounds__(512, 1) void k_seq(
    const float* __restrict__ zpart, const float* __restrict__ soc_init,
    const float* __restrict__ current, const float* __restrict__ vmeas,
    const float* __restrict__ u, const float* __restrict__ noise,
    const float* __restrict__ b3, float* __restrict__ vbuf,
    float* __restrict__ sbuf, float* __restrict__ out)
{
    const int tid = threadIdx.x;
    const int lane = tid & 63;
    const int wid = tid >> 6;

    __shared__ float zt[ROWS];        // per-t 1-D tables [128][33]
    __shared__ float zt2d[TAB2D];     // [s_idx][I_idx]
    __shared__ float socs[2][512];
    __shared__ int marker[512];
    __shared__ float cur_s[128], vm_s[128], u_s[128];
    __shared__ float redM[8], redT[8];

    float bb3 = b3[0];
    for (int j = tid; j < TAB2D; j += 512) zt2d[j] = zpart[j] + zpart[TAB2D + j] + bb3;
    if (tid < 128) { cur_s[tid] = current[tid]; vm_s[tid] = vmeas[tid]; u_s[tid] = u[tid]; }
    marker[tid] = 0;
    __syncthreads();

    // collapse: zt[t][g] = cubic-in-I( zt2d[g][.], I_t )
    for (int idx = tid; idx < ROWS; idx += 512) {
        int t = idx / G_NODES;
        int g = idx - t * G_NODES;
        zt[idx] = interp_tab(&zt2d[g * G_NODES], 1, cur_s[t]);
    }
    __syncthreads();

    float soc = soc_init[tid];
    float Iprev = cur_s[0];
    float V = vocf(soc) - Iprev * interp_tab(&zt[0], 1, soc);
    float loss_acc = 0.f;
    const float LOG_NU = logf(19.947114020071635f);
    const float LOG_N = logf(512.f);

    float nz_cur = noise[tid];

    for (int t = 0; t < T_STEPS; ++t) {
        int tn = (t + 1 < T_STEPS) ? t + 1 : t;
        float nz_next = noise[tn * 512 + tid];   // stays in flight across light barriers

        // ---- A: propagate, V, logW, wave max + scan ----
        soc = soc - Iprev * V * E_CRIT_INV + F_STD * nz_cur;
        soc = soc > 1.f ? 1.f : (soc < 0.f ? 1e-10f : soc);
        socs[t & 1][tid] = soc;

        float I = cur_s[t];
        V = vocf(soc) - I * interp_tab(&zt[t * G_NODES], 1, soc);
        float d = (V - vm_s[t]) * (1.f / G_STD);
        float lw = LOG_NU - 0.5f * d * d;

        float m = wave_max_f(lw);
        float e = expf(lw - m);
        float incl = wave_scan_add(e, lane);
        if (lane == 63) { redM[wid] = m; redT[wid] = incl; }
        LBAR();                                            // barrier 1 (LDS only)

        // ---- B: lane-parallel cross-wave combine ----
        float rm = redM[lane & 7];
        float rt = redT[lane & 7];
        float M = rm;   // 16-lane row rotation max == max(redM[0..7])
        M = fmaxf(M, __int_as_float(dpp_ror<1>(__float_as_int(M))));
        M = fmaxf(M, __int_as_float(dpp_ror<2>(__float_as_int(M))));
        M = fmaxf(M, __int_as_float(dpp_ror<4>(__float_as_int(M))));
        M = fmaxf(M, __int_as_float(dpp_ror<8>(__float_as_int(M))));
        float fw = expf(rm - M);
        float term = rt * fw;
        float sc = term;   // 8-lane inclusive prefix (valid for lanes 0..7)
        sc += __int_as_float(dpp_shr<1>(__float_as_int(sc)));
        sc += __int_as_float(dpp_shr<2>(__float_as_int(sc)));
        sc += __int_as_float(dpp_shr<4>(__float_as_int(sc)));
        float S = __int_as_float(__builtin_amdgcn_readlane(__float_as_int(sc), 7));
        float off = 0.f;
        if (wid > 0) off = __int_as_float(__builtin_amdgcn_readlane(__float_as_int(sc), wid - 1));
        float fw_own = __int_as_float(__builtin_amdgcn_readlane(__float_as_int(fw), wid));
        loss_acc += M + logf(S) - LOG_N;

        float C = 512.f * ((off + incl * fw_own) / S);
        int hi = count_le(C, u_s[t]);
        if (hi < 512) atomicMax(&marker[hi], (t << 10) | (tid + 1));
        LBAR();                                            // barrier 2 (LDS only)

        // ---- C: owner via max-scan of markers, gather, coalesced stores ----
        int pm = 0;
        for (int w = 0; w < wid; ++w) pm = max(pm, marker[w * 64 + lane]);
        pm = wave_max_i(pm);
        int v = wave_scanmax_i(marker[tid], lane);
        int sv = max(v, pm);
        int owner = ((sv >> 10) == t) ? (sv & 1023) : 0;
        owner = owner > 511 ? 511 : owner;
        float socr = socs[t & 1][owner];

        vbuf[t * 512 + tid] = V;
        sbuf[t * 512 + tid] = socr;
        soc = socr;
        Iprev = I;
        nz_cur = nz_next;
    }
    if (tid == 0) out[0] = loss_acc;
}

// ---------------------------------------------------------------------------
// Phase C: transpose time-major [128][512] -> particle-major [512][128]
// ---------------------------------------------------------------------------
__global__ __launch_bounds__(256) void k_fin(
    const float* __restrict__ vbuf, const float* __restrict__ sbuf,
    float* __restrict__ out)
{
    __shared__ float tile[32][33];
    int tz = blockIdx.z;
    int t0 = blockIdx.x * 32;
    int i0 = blockIdx.y * 32;
    const float* src = tz ? sbuf : vbuf;
    float* dst = out + 1 + tz * (N_PART * T_STEPS);
    int tx = threadIdx.x & 31, ty = threadIdx.x >> 5;
    #pragma unroll
    for (int m2 = 0; m2 < 4; ++m2)
        tile[ty + 8 * m2][tx] = src[(t0 + ty + 8 * m2) * 512 + i0 + tx];
    __syncthreads();
    #pragma unroll
    for (int m2 = 0; m2 < 4; ++m2)
        dst[(i0 + ty + 8 * m2) * 128 + t0 + tx] = tile[tx][ty + 8 * m2];
}

extern "C" void kernel_launch(void* const* d_in, const int* in_sizes, int n_in,
                              void* d_out, int out_size, void* d_ws, size_t ws_size,
                              hipStream_t stream)
{
    const float* soc_init = (const float*)d_in[0];
    const float* current  = (const float*)d_in[1];
    const float* vmeas    = (const float*)d_in[2];
    const float* noise    = (const float*)d_in[3];
    const float* u        = (const float*)d_in[4];
    const float* w1 = (const float*)d_in[5];
    const float* b1 = (const float*)d_in[6];
    const float* w2 = (const float*)d_in[7];
    const float* b2 = (const float*)d_in[8];
    const float* w3 = (const float*)d_in[9];
    const float* b3 = (const float*)d_in[10];
    float* out = (float*)d_out;
    float* ws  = (float*)d_ws;

    float* zpart = ws;                       // 2*TAB2D floats
    float* vbuf  = ws + 2 * TAB2D;           // 65536 floats
    float* sbuf  = vbuf + N_PART * T_STEPS;  // 65536 floats

    k_tab<<<274, 256, 0, stream>>>(w1, b1, w2, b2, w3, zpart);
    k_seq<<<1, 512, 0, stream>>>(zpart, soc_init, current, vmeas, u, noise, b3,
                                 vbuf, sbuf, out);
    k_fin<<<dim3(4, 16, 2), 256, 0, stream>>>(vbuf, sbuf, out);
}